// Round 2
// baseline (1708.483 us; speedup 1.0000x reference)
//
#include <hip/hip_runtime.h>
#include <hip/hip_fp16.h>

#define NODES 100000
#define DIM 128
#define KSTEPS 10
#define CAP 128          // fixed CSR slot capacity; max in-degree ~Poisson(32) -> ~65 max

// Bucketed build: NBUCKET dst-ranges of 256 nodes, 8 pseudo-XCD sub-buckets each.
#define BSHIFT 8                     // 256 nodes per range
#define NBUCKET 391                  // ceil(100000/256)
#define BCAP 1536                    // mean ~1024 per (g,b), +16 sigma headroom

// ---------- build phase A: append packed (src,dst_local) into buckets ----------
// pseudo-XCD g = blockIdx&7 keeps each bucket's cursor-front lines in one L2
// (round-robin heuristic; perf-only). Writes coalesce at cursor fronts:
// ~12.8 MB payload instead of ~290 MB of dirtied lines from random CSR scatter.
__global__ void bucket_kernel(const int* __restrict__ src, const int* __restrict__ dst,
                              int* __restrict__ outc, int* __restrict__ bcnt,
                              unsigned* __restrict__ pairs, int E) {
    int g = blockIdx.x & 7;
    int i = blockIdx.x * blockDim.x + threadIdx.x;
    int stride = gridDim.x * blockDim.x;
    for (; i < E; i += stride) {
        int s_ = src[i];
        int d_ = dst[i];
        atomicAdd(&outc[s_], 1);
        int b = d_ >> BSHIFT;
        int cidx = g * NBUCKET + b;
        int slot = atomicAdd(&bcnt[cidx], 1);
        if (slot < BCAP)
            pairs[(size_t)cidx * BCAP + slot] = ((unsigned)s_ << 8) | (unsigned)(d_ & 255);
    }
}

// ---------- build phase B: scatter within a 256-node (128 KB CSR) window ----------
// 2 blocks per range (sub-buckets 0-3 / 4-7). All CSR writes of a block stay
// inside a 128 KB window -> lines stay L2-resident and coalesce before write-back.
// cur[d] ends at the true in-degree (CAP=128 > max observed ~65, no drops).
__global__ void scatter_kernel(const int* __restrict__ bcnt, const unsigned* __restrict__ pairs,
                               int* __restrict__ cur, int* __restrict__ csr) {
    int r = blockIdx.x >> 1;             // dst range
    int gbase = (blockIdx.x & 1) * 4;    // 4 sub-buckets per block
    int base = r << BSHIFT;
    for (int gi = 0; gi < 4; ++gi) {
        int cidx = (gbase + gi) * NBUCKET + r;
        int cnt = bcnt[cidx];
        if (cnt > BCAP) cnt = BCAP;
        const unsigned* p = pairs + (size_t)cidx * BCAP;
        for (int i = threadIdx.x; i < cnt; i += blockDim.x) {
            unsigned v = p[i];
            int d_ = base + (int)(v & 255u);
            int s_ = (int)(v >> 8);
            int c = atomicAdd(&cur[d_], 1);
            if (c < CAP) csr[((size_t)d_ << 7) + c] = s_;
        }
    }
}

// norms: src_norm = rsqrt(max(outdeg,1)); isrc = 1/src_norm; dst_norm = rsqrt(max(indeg,1))
__global__ void norm_kernel(const int* __restrict__ outc, const int* __restrict__ inc,
                            float* __restrict__ src_norm, float* __restrict__ isrc,
                            float* __restrict__ dst_norm, int n) {
    int i = blockIdx.x * blockDim.x + threadIdx.x;
    if (i < n) {
        float od = fmaxf((float)outc[i], 1.0f);
        float id = fmaxf((float)inc[i], 1.0f);
        float sn = rsqrtf(od);
        src_norm[i] = sn;
        isrc[i] = sqrtf(od);
        dst_norm[i] = rsqrtf(id);
    }
}

// main path k=0: sg0 = sigmoid(<feats,s>); p0 = src_norm * feats (fp16). No out write.
__global__ void combine0_main(const float* __restrict__ feats, const float* __restrict__ s,
                              const float* __restrict__ src_norm,
                              __half* __restrict__ p0, float* __restrict__ sg0, int n) {
    int lane = threadIdx.x & 63;
    int wave = (blockIdx.x * blockDim.x + threadIdx.x) >> 6;
    int nwaves = (gridDim.x * blockDim.x) >> 6;
    float2 sv = *(const float2*)(s + lane * 2);
    for (int node = wave; node < n; node += nwaves) {
        float2 hv = *(const float2*)(feats + (size_t)node * DIM + lane * 2);
        float sn = src_norm[node];
        __half2 ph; ph.x = __float2half(sn * hv.x); ph.y = __float2half(sn * hv.y);
        *(__half2*)(p0 + (size_t)node * DIM + lane * 2) = ph;
        float dot = hv.x * sv.x + hv.y * sv.y;
        #pragma unroll
        for (int off = 32; off > 0; off >>= 1) dot += __shfl_xor(dot, off);
        if (lane == 0) sg0[node] = 1.0f / (1.0f + expf(-dot));
    }
}

// fallback k=0: out = sigmoid(<feats,s>)*feats; p0 = src_norm*feats
__global__ void combine0_fb(const float* __restrict__ feats, const float* __restrict__ s,
                            const float* __restrict__ src_norm,
                            __half* __restrict__ p0, float* __restrict__ out, int n) {
    int lane = threadIdx.x & 63;
    int wave = (blockIdx.x * blockDim.x + threadIdx.x) >> 6;
    int nwaves = (gridDim.x * blockDim.x) >> 6;
    float2 sv = *(const float2*)(s + lane * 2);
    for (int node = wave; node < n; node += nwaves) {
        float2 hv = *(const float2*)(feats + (size_t)node * DIM + lane * 2);
        float sn = src_norm[node];
        __half2 ph; ph.x = __float2half(sn * hv.x); ph.y = __float2half(sn * hv.y);
        *(__half2*)(p0 + (size_t)node * DIM + lane * 2) = ph;
        float dot = hv.x * sv.x + hv.y * sv.y;
        #pragma unroll
        for (int off = 32; off > 0; off >>= 1) dot += __shfl_xor(dot, off);
        float sg = 1.0f / (1.0f + expf(-dot));
        float2 ov; ov.x = sg * hv.x; ov.y = sg * hv.y;
        *(float2*)(out + (size_t)node * DIM + lane * 2) = ov;
    }
}

// One wave per node. raw = sum_{e in slots} p_prev[src_e]; h = dst_norm*raw;
// sg_k[n] = sigmoid(<h,s>); p_next = src_norm*h (fp16).
__global__ void gather_main(const __half* __restrict__ pprev,
                            const float* __restrict__ src_norm, const float* __restrict__ dst_norm,
                            const int* __restrict__ cnt, const int* __restrict__ csr,
                            const float* __restrict__ s,
                            __half* __restrict__ pnext, float* __restrict__ sgk, int n) {
    int lane = threadIdx.x & 63;
    int wave = (blockIdx.x * blockDim.x + threadIdx.x) >> 6;
    int nwaves = (gridDim.x * blockDim.x) >> 6;
    float2 sv = *(const float2*)(s + lane * 2);
    for (int node = wave; node < n; node += nwaves) {
        int c = cnt[node]; if (c > CAP) c = CAP;
        const int* row = csr + ((size_t)node << 7);
        float accx = 0.0f, accy = 0.0f;
        int p = 0;
        for (; p + 7 < c; p += 8) {
            int s0 = row[p], s1 = row[p+1], s2 = row[p+2], s3 = row[p+3];
            int s4 = row[p+4], s5 = row[p+5], s6 = row[p+6], s7 = row[p+7];
            float2 f0 = __half22float2(*(const __half2*)(pprev + (size_t)s0 * DIM + lane * 2));
            float2 f1 = __half22float2(*(const __half2*)(pprev + (size_t)s1 * DIM + lane * 2));
            float2 f2 = __half22float2(*(const __half2*)(pprev + (size_t)s2 * DIM + lane * 2));
            float2 f3 = __half22float2(*(const __half2*)(pprev + (size_t)s3 * DIM + lane * 2));
            float2 f4 = __half22float2(*(const __half2*)(pprev + (size_t)s4 * DIM + lane * 2));
            float2 f5 = __half22float2(*(const __half2*)(pprev + (size_t)s5 * DIM + lane * 2));
            float2 f6 = __half22float2(*(const __half2*)(pprev + (size_t)s6 * DIM + lane * 2));
            float2 f7 = __half22float2(*(const __half2*)(pprev + (size_t)s7 * DIM + lane * 2));
            accx += f0.x + f1.x + f2.x + f3.x + f4.x + f5.x + f6.x + f7.x;
            accy += f0.y + f1.y + f2.y + f3.y + f4.y + f5.y + f6.y + f7.y;
        }
        for (; p < c; ++p) {
            int si = row[p];
            float2 fv = __half22float2(*(const __half2*)(pprev + (size_t)si * DIM + lane * 2));
            accx += fv.x; accy += fv.y;
        }
        float dn = dst_norm[node];
        float hx = dn * accx, hy = dn * accy;
        float dot = hx * sv.x + hy * sv.y;
        #pragma unroll
        for (int off = 32; off > 0; off >>= 1) dot += __shfl_xor(dot, off);
        if (lane == 0) sgk[node] = 1.0f / (1.0f + expf(-dot));
        float sn = src_norm[node];
        __half2 pw; pw.x = __float2half(sn * hx); pw.y = __float2half(sn * hy);
        *(__half2*)(pnext + (size_t)node * DIM + lane * 2) = pw;
    }
}

// fallback: same gather, but out += sg*h in-loop, no sg storage
__global__ void gather_fb(const __half* __restrict__ pprev,
                          const float* __restrict__ src_norm, const float* __restrict__ dst_norm,
                          const int* __restrict__ cnt, const int* __restrict__ csr,
                          const float* __restrict__ s,
                          __half* __restrict__ pnext, float* __restrict__ out, int n) {
    int lane = threadIdx.x & 63;
    int wave = (blockIdx.x * blockDim.x + threadIdx.x) >> 6;
    int nwaves = (gridDim.x * blockDim.x) >> 6;
    float2 sv = *(const float2*)(s + lane * 2);
    for (int node = wave; node < n; node += nwaves) {
        int c = cnt[node]; if (c > CAP) c = CAP;
        const int* row = csr + ((size_t)node << 7);
        float accx = 0.0f, accy = 0.0f;
        int p = 0;
        for (; p + 7 < c; p += 8) {
            int s0 = row[p], s1 = row[p+1], s2 = row[p+2], s3 = row[p+3];
            int s4 = row[p+4], s5 = row[p+5], s6 = row[p+6], s7 = row[p+7];
            float2 f0 = __half22float2(*(const __half2*)(pprev + (size_t)s0 * DIM + lane * 2));
            float2 f1 = __half22float2(*(const __half2*)(pprev + (size_t)s1 * DIM + lane * 2));
            float2 f2 = __half22float2(*(const __half2*)(pprev + (size_t)s2 * DIM + lane * 2));
            float2 f3 = __half22float2(*(const __half2*)(pprev + (size_t)s3 * DIM + lane * 2));
            float2 f4 = __half22float2(*(const __half2*)(pprev + (size_t)s4 * DIM + lane * 2));
            float2 f5 = __half22float2(*(const __half2*)(pprev + (size_t)s5 * DIM + lane * 2));
            float2 f6 = __half22float2(*(const __half2*)(pprev + (size_t)s6 * DIM + lane * 2));
            float2 f7 = __half22float2(*(const __half2*)(pprev + (size_t)s7 * DIM + lane * 2));
            accx += f0.x + f1.x + f2.x + f3.x + f4.x + f5.x + f6.x + f7.x;
            accy += f0.y + f1.y + f2.y + f3.y + f4.y + f5.y + f6.y + f7.y;
        }
        for (; p < c; ++p) {
            int si = row[p];
            float2 fv = __half22float2(*(const __half2*)(pprev + (size_t)si * DIM + lane * 2));
            accx += fv.x; accy += fv.y;
        }
        float dn = dst_norm[node];
        float hx = dn * accx, hy = dn * accy;
        float dot = hx * sv.x + hy * sv.y;
        #pragma unroll
        for (int off = 32; off > 0; off >>= 1) dot += __shfl_xor(dot, off);
        float sg = 1.0f / (1.0f + expf(-dot));
        float2 ov = *(float2*)(out + (size_t)node * DIM + lane * 2);
        ov.x += sg * hx; ov.y += sg * hy;
        *(float2*)(out + (size_t)node * DIM + lane * 2) = ov;
        float sn = src_norm[node];
        __half2 pw; pw.x = __float2half(sn * hx); pw.y = __float2half(sn * hy);
        *(__half2*)(pnext + (size_t)node * DIM + lane * 2) = pw;
    }
}

// final: out[n] = sum_k sg_k[n] * (p_k[n] * isrc[n])   (h_k = p_k / src_norm)
__global__ void final_combine(const __half* __restrict__ pbase, const float* __restrict__ sg,
                              const float* __restrict__ isrc, float* __restrict__ out, int n) {
    int lane = threadIdx.x & 63;
    int wave = (blockIdx.x * blockDim.x + threadIdx.x) >> 6;
    int nwaves = (gridDim.x * blockDim.x) >> 6;
    for (int node = wave; node < n; node += nwaves) {
        float iv = isrc[node];
        float ax = 0.0f, ay = 0.0f;
        #pragma unroll
        for (int k = 0; k <= KSTEPS; ++k) {
            float g = sg[(size_t)k * n + node] * iv;
            float2 fv = __half22float2(
                *(const __half2*)(pbase + ((size_t)k * n + node) * DIM + lane * 2));
            ax += g * fv.x; ay += g * fv.y;
        }
        *(float2*)(out + (size_t)node * DIM + lane * 2) = make_float2(ax, ay);
    }
}

extern "C" void kernel_launch(void* const* d_in, const int* in_sizes, int n_in,
                              void* d_out, int out_size, void* d_ws, size_t ws_size,
                              hipStream_t stream) {
    const float* feats = (const float*)d_in[0];
    const float* s     = (const float*)d_in[1];
    const int*   src   = (const int*)d_in[2];
    const int*   dst   = (const int*)d_in[3];
    float* out = (float*)d_out;
    const int E = in_sizes[2];

    // Workspace layout
    int*   outc     = (int*)d_ws;                         // N
    int*   cur      = outc + NODES;                       // N (in-degree after build)
    float* src_norm = (float*)(cur + NODES);              // N
    float* isrc     = src_norm + NODES;                   // N
    float* dst_norm = isrc + NODES;                       // N
    float* sg       = dst_norm + NODES;                   // 11*N
    int*   csr      = (int*)(sg + (size_t)(KSTEPS + 1) * NODES);   // N*CAP
    __half* pbase   = (__half*)(csr + (size_t)NODES * CAP);

    const size_t head_bytes = (size_t)(2 * NODES) * 4 + (size_t)(3 + KSTEPS + 1) * NODES * 4
                            + (size_t)NODES * CAP * 4;
    const size_t pbuf = (size_t)NODES * DIM * sizeof(__half);   // 25.6 MB each
    const bool main_path = ws_size >= head_bytes + (size_t)(KSTEPS + 1) * pbuf;

    // Bucket storage aliased over the FIRST p-slab (p0). In both paths p0 is
    // written only by combine0_* which runs after scatter_kernel completes
    // (stream-ordered), so the aliasing is safe everywhere.
    // bcnt: 8*NBUCKET ints (~12.5 KB); pairs: 8*NBUCKET*BCAP u32 (~19.2 MB) < 25.6 MB slab.
    int* bcnt = (int*)pbase;
    unsigned* pairs = (unsigned*)(bcnt + 8 * NBUCKET);

    hipMemsetAsync(outc, 0, 2 * NODES * sizeof(int), stream);
    hipMemsetAsync(bcnt, 0, 8 * NBUCKET * sizeof(int), stream);
    bucket_kernel<<<2048, 256, 0, stream>>>(src, dst, outc, bcnt, pairs, E);
    scatter_kernel<<<2 * NBUCKET, 256, 0, stream>>>(bcnt, pairs, cur, csr);
    norm_kernel<<<(NODES + 255) / 256, 256, 0, stream>>>(outc, cur, src_norm, isrc, dst_norm, NODES);

    const int ngrid = (NODES * 64 + 255) / 256;
    if (main_path) {
        // p_k stored contiguously: p_k = pbase + k*N*D
        combine0_main<<<ngrid, 256, 0, stream>>>(feats, s, src_norm, pbase, sg, NODES);
        for (int k = 1; k <= KSTEPS; ++k) {
            const __half* pprev = pbase + (size_t)(k - 1) * NODES * DIM;
            __half* pnext = pbase + (size_t)k * NODES * DIM;
            gather_main<<<ngrid, 256, 0, stream>>>(pprev, src_norm, dst_norm, cur, csr, s,
                                                   pnext, sg + (size_t)k * NODES, NODES);
        }
        final_combine<<<ngrid, 256, 0, stream>>>(pbase, sg, isrc, out, NODES);
    } else {
        __half* pA = pbase;
        __half* pB = pbase + (size_t)NODES * DIM;
        combine0_fb<<<ngrid, 256, 0, stream>>>(feats, s, src_norm, pA, out, NODES);
        const __half* pcur = pA;
        for (int k = 1; k <= KSTEPS; ++k) {
            __half* pnext = (k & 1) ? pB : pA;
            gather_fb<<<ngrid, 256, 0, stream>>>(pcur, src_norm, dst_norm, cur, csr, s,
                                                 pnext, out, NODES);
            pcur = pnext;
        }
    }
}

// Round 3
// 1516.920 us; speedup vs baseline: 1.1263x; 1.1263x over previous
//
#include <hip/hip_runtime.h>
#include <hip/hip_fp16.h>

#define NODES 100000
#define DIM 128
#define KSTEPS 10
#define CAP 128          // fixed CSR slot capacity; max in-degree ~Poisson(32) -> ~65 max

// Block-aggregated binning: NR coarse ranges of RANGE nodes.
#define RSHIFT 11
#define RANGE 2048                   // nodes per range (CSR window = 1 MB, L2-resident)
#define NR 49                        // ceil(100000/2048)
#define GBCAP 72000                  // mean E/NR ~65.3K, sigma ~254 -> +26 sigma headroom
#define VPT 16                       // edges per thread per batch
#define BT (256 * VPT)               // 4096 edges per block-batch

// ---------- build phase A: block-aggregated two-stream binning ----------
// Per-edge work uses only LDS atomics (rank within batch). One global atomic
// per (block,bucket) reserves a contiguous chunk, so each ~84-entry run is
// written by a single block -> lines fill in one XCD's L2 before write-back.
// Global atomics: ~2*NR per 4096-edge batch (~96K total vs 6.4M before).
__global__ void bucket_agg(const int* __restrict__ src, const int* __restrict__ dst,
                           unsigned* __restrict__ gdc, unsigned* __restrict__ gsc,
                           unsigned* __restrict__ dpairs, unsigned* __restrict__ spairs, int E) {
    __shared__ unsigned dcnt[NR], scnt[NR], dbase[NR], sbase[NR];
    const int tid = threadIdx.x;
    if (tid < NR) { dcnt[tid] = 0; scnt[tid] = 0; }
    __syncthreads();

    const int base = blockIdx.x * BT;
    int dv[VPT], sv[VPT];
    unsigned rd[VPT], rs[VPT];
    #pragma unroll
    for (int j = 0; j < VPT; ++j) {
        int i = base + tid + j * 256;
        if (i < E) {
            int d_ = dst[i]; int s_ = src[i];
            dv[j] = d_; sv[j] = s_;
            rd[j] = atomicAdd(&dcnt[d_ >> RSHIFT], 1u);
            rs[j] = atomicAdd(&scnt[s_ >> RSHIFT], 1u);
        }
    }
    __syncthreads();
    if (tid < NR) {
        unsigned c = dcnt[tid];
        dbase[tid] = c ? atomicAdd(&gdc[tid], c) : 0u;
    } else if (tid >= 64 && tid < 64 + NR) {
        int b = tid - 64;
        unsigned c = scnt[b];
        sbase[b] = c ? atomicAdd(&gsc[b], c) : 0u;
    }
    __syncthreads();
    #pragma unroll
    for (int j = 0; j < VPT; ++j) {
        int i = base + tid + j * 256;
        if (i < E) {
            int d_ = dv[j]; int s_ = sv[j];
            int b = d_ >> RSHIFT;
            unsigned pos = dbase[b] + rd[j];
            if (pos < GBCAP)
                dpairs[(size_t)b * GBCAP + pos] =
                    ((unsigned)s_ << RSHIFT) | (unsigned)(d_ & (RANGE - 1));
            int bs = s_ >> RSHIFT;
            unsigned ps = sbase[bs] + rs[j];
            if (ps < GBCAP)
                spairs[(size_t)bs * GBCAP + ps] = (unsigned)(s_ & (RANGE - 1));
        }
    }
}

// ---------- build phase B: per-range CSR scatter + degrees, LDS counters only ----------
// blockIdx even -> dst part: LDS cursors give CSR slots (all writes inside a
// 1 MB L2-resident window); cur[node] = in-degree written once, coalesced.
// blockIdx odd  -> src part: LDS histogram -> outc[node] written once.
__global__ void degree_scatter(const unsigned* __restrict__ gdc, const unsigned* __restrict__ gsc,
                               const unsigned* __restrict__ dpairs, const unsigned* __restrict__ spairs,
                               int* __restrict__ cur, int* __restrict__ outc,
                               int* __restrict__ csr) {
    __shared__ int ctr[RANGE];
    const int r = blockIdx.x >> 1;
    const int nodebase = r << RSHIFT;
    for (int i = threadIdx.x; i < RANGE; i += blockDim.x) ctr[i] = 0;
    __syncthreads();
    if ((blockIdx.x & 1) == 0) {
        int cnt = (int)gdc[r]; if (cnt > GBCAP) cnt = GBCAP;
        const unsigned* p = dpairs + (size_t)r * GBCAP;
        for (int i = threadIdx.x; i < cnt; i += blockDim.x) {
            unsigned v = p[i];
            int dloc = (int)(v & (RANGE - 1));
            int s_ = (int)(v >> RSHIFT);
            int slot = atomicAdd(&ctr[dloc], 1);
            if (slot < CAP) csr[((size_t)(nodebase + dloc) << 7) + slot] = s_;
        }
        __syncthreads();
        for (int i = threadIdx.x; i < RANGE; i += blockDim.x) {
            int node = nodebase + i;
            if (node < NODES) cur[node] = ctr[i];
        }
    } else {
        int cnt = (int)gsc[r]; if (cnt > GBCAP) cnt = GBCAP;
        const unsigned* p = spairs + (size_t)r * GBCAP;
        for (int i = threadIdx.x; i < cnt; i += blockDim.x)
            atomicAdd(&ctr[p[i]], 1);
        __syncthreads();
        for (int i = threadIdx.x; i < RANGE; i += blockDim.x) {
            int node = nodebase + i;
            if (node < NODES) outc[node] = ctr[i];
        }
    }
}

// norms: src_norm = rsqrt(max(outdeg,1)); isrc = 1/src_norm; dst_norm = rsqrt(max(indeg,1))
__global__ void norm_kernel(const int* __restrict__ outc, const int* __restrict__ inc,
                            float* __restrict__ src_norm, float* __restrict__ isrc,
                            float* __restrict__ dst_norm, int n) {
    int i = blockIdx.x * blockDim.x + threadIdx.x;
    if (i < n) {
        float od = fmaxf((float)outc[i], 1.0f);
        float id = fmaxf((float)inc[i], 1.0f);
        float sn = rsqrtf(od);
        src_norm[i] = sn;
        isrc[i] = sqrtf(od);
        dst_norm[i] = rsqrtf(id);
    }
}

// main path k=0: sg0 = sigmoid(<feats,s>); p0 = src_norm * feats (fp16). No out write.
__global__ void combine0_main(const float* __restrict__ feats, const float* __restrict__ s,
                              const float* __restrict__ src_norm,
                              __half* __restrict__ p0, float* __restrict__ sg0, int n) {
    int lane = threadIdx.x & 63;
    int wave = (blockIdx.x * blockDim.x + threadIdx.x) >> 6;
    int nwaves = (gridDim.x * blockDim.x) >> 6;
    float2 sv = *(const float2*)(s + lane * 2);
    for (int node = wave; node < n; node += nwaves) {
        float2 hv = *(const float2*)(feats + (size_t)node * DIM + lane * 2);
        float sn = src_norm[node];
        __half2 ph; ph.x = __float2half(sn * hv.x); ph.y = __float2half(sn * hv.y);
        *(__half2*)(p0 + (size_t)node * DIM + lane * 2) = ph;
        float dot = hv.x * sv.x + hv.y * sv.y;
        #pragma unroll
        for (int off = 32; off > 0; off >>= 1) dot += __shfl_xor(dot, off);
        if (lane == 0) sg0[node] = 1.0f / (1.0f + expf(-dot));
    }
}

// fallback k=0: out = sigmoid(<feats,s>)*feats; p0 = src_norm*feats
__global__ void combine0_fb(const float* __restrict__ feats, const float* __restrict__ s,
                            const float* __restrict__ src_norm,
                            __half* __restrict__ p0, float* __restrict__ out, int n) {
    int lane = threadIdx.x & 63;
    int wave = (blockIdx.x * blockDim.x + threadIdx.x) >> 6;
    int nwaves = (gridDim.x * blockDim.x) >> 6;
    float2 sv = *(const float2*)(s + lane * 2);
    for (int node = wave; node < n; node += nwaves) {
        float2 hv = *(const float2*)(feats + (size_t)node * DIM + lane * 2);
        float sn = src_norm[node];
        __half2 ph; ph.x = __float2half(sn * hv.x); ph.y = __float2half(sn * hv.y);
        *(__half2*)(p0 + (size_t)node * DIM + lane * 2) = ph;
        float dot = hv.x * sv.x + hv.y * sv.y;
        #pragma unroll
        for (int off = 32; off > 0; off >>= 1) dot += __shfl_xor(dot, off);
        float sg = 1.0f / (1.0f + expf(-dot));
        float2 ov; ov.x = sg * hv.x; ov.y = sg * hv.y;
        *(float2*)(out + (size_t)node * DIM + lane * 2) = ov;
    }
}

// One wave per node. raw = sum_{e in slots} p_prev[src_e]; h = dst_norm*raw;
// sg_k[n] = sigmoid(<h,s>); p_next = src_norm*h (fp16).
__global__ void gather_main(const __half* __restrict__ pprev,
                            const float* __restrict__ src_norm, const float* __restrict__ dst_norm,
                            const int* __restrict__ cnt, const int* __restrict__ csr,
                            const float* __restrict__ s,
                            __half* __restrict__ pnext, float* __restrict__ sgk, int n) {
    int lane = threadIdx.x & 63;
    int wave = (blockIdx.x * blockDim.x + threadIdx.x) >> 6;
    int nwaves = (gridDim.x * blockDim.x) >> 6;
    float2 sv = *(const float2*)(s + lane * 2);
    for (int node = wave; node < n; node += nwaves) {
        int c = cnt[node]; if (c > CAP) c = CAP;
        const int* row = csr + ((size_t)node << 7);
        float accx = 0.0f, accy = 0.0f;
        int p = 0;
        for (; p + 7 < c; p += 8) {
            int s0 = row[p], s1 = row[p+1], s2 = row[p+2], s3 = row[p+3];
            int s4 = row[p+4], s5 = row[p+5], s6 = row[p+6], s7 = row[p+7];
            float2 f0 = __half22float2(*(const __half2*)(pprev + (size_t)s0 * DIM + lane * 2));
            float2 f1 = __half22float2(*(const __half2*)(pprev + (size_t)s1 * DIM + lane * 2));
            float2 f2 = __half22float2(*(const __half2*)(pprev + (size_t)s2 * DIM + lane * 2));
            float2 f3 = __half22float2(*(const __half2*)(pprev + (size_t)s3 * DIM + lane * 2));
            float2 f4 = __half22float2(*(const __half2*)(pprev + (size_t)s4 * DIM + lane * 2));
            float2 f5 = __half22float2(*(const __half2*)(pprev + (size_t)s5 * DIM + lane * 2));
            float2 f6 = __half22float2(*(const __half2*)(pprev + (size_t)s6 * DIM + lane * 2));
            float2 f7 = __half22float2(*(const __half2*)(pprev + (size_t)s7 * DIM + lane * 2));
            accx += f0.x + f1.x + f2.x + f3.x + f4.x + f5.x + f6.x + f7.x;
            accy += f0.y + f1.y + f2.y + f3.y + f4.y + f5.y + f6.y + f7.y;
        }
        for (; p < c; ++p) {
            int si = row[p];
            float2 fv = __half22float2(*(const __half2*)(pprev + (size_t)si * DIM + lane * 2));
            accx += fv.x; accy += fv.y;
        }
        float dn = dst_norm[node];
        float hx = dn * accx, hy = dn * accy;
        float dot = hx * sv.x + hy * sv.y;
        #pragma unroll
        for (int off = 32; off > 0; off >>= 1) dot += __shfl_xor(dot, off);
        if (lane == 0) sgk[node] = 1.0f / (1.0f + expf(-dot));
        float sn = src_norm[node];
        __half2 pw; pw.x = __float2half(sn * hx); pw.y = __float2half(sn * hy);
        *(__half2*)(pnext + (size_t)node * DIM + lane * 2) = pw;
    }
}

// fallback: same gather, but out += sg*h in-loop, no sg storage
__global__ void gather_fb(const __half* __restrict__ pprev,
                          const float* __restrict__ src_norm, const float* __restrict__ dst_norm,
                          const int* __restrict__ cnt, const int* __restrict__ csr,
                          const float* __restrict__ s,
                          __half* __restrict__ pnext, float* __restrict__ out, int n) {
    int lane = threadIdx.x & 63;
    int wave = (blockIdx.x * blockDim.x + threadIdx.x) >> 6;
    int nwaves = (gridDim.x * blockDim.x) >> 6;
    float2 sv = *(const float2*)(s + lane * 2);
    for (int node = wave; node < n; node += nwaves) {
        int c = cnt[node]; if (c > CAP) c = CAP;
        const int* row = csr + ((size_t)node << 7);
        float accx = 0.0f, accy = 0.0f;
        int p = 0;
        for (; p + 7 < c; p += 8) {
            int s0 = row[p], s1 = row[p+1], s2 = row[p+2], s3 = row[p+3];
            int s4 = row[p+4], s5 = row[p+5], s6 = row[p+6], s7 = row[p+7];
            float2 f0 = __half22float2(*(const __half2*)(pprev + (size_t)s0 * DIM + lane * 2));
            float2 f1 = __half22float2(*(const __half2*)(pprev + (size_t)s1 * DIM + lane * 2));
            float2 f2 = __half22float2(*(const __half2*)(pprev + (size_t)s2 * DIM + lane * 2));
            float2 f3 = __half22float2(*(const __half2*)(pprev + (size_t)s3 * DIM + lane * 2));
            float2 f4 = __half22float2(*(const __half2*)(pprev + (size_t)s4 * DIM + lane * 2));
            float2 f5 = __half22float2(*(const __half2*)(pprev + (size_t)s5 * DIM + lane * 2));
            float2 f6 = __half22float2(*(const __half2*)(pprev + (size_t)s6 * DIM + lane * 2));
            float2 f7 = __half22float2(*(const __half2*)(pprev + (size_t)s7 * DIM + lane * 2));
            accx += f0.x + f1.x + f2.x + f3.x + f4.x + f5.x + f6.x + f7.x;
            accy += f0.y + f1.y + f2.y + f3.y + f4.y + f5.y + f6.y + f7.y;
        }
        for (; p < c; ++p) {
            int si = row[p];
            float2 fv = __half22float2(*(const __half2*)(pprev + (size_t)si * DIM + lane * 2));
            accx += fv.x; accy += fv.y;
        }
        float dn = dst_norm[node];
        float hx = dn * accx, hy = dn * accy;
        float dot = hx * sv.x + hy * sv.y;
        #pragma unroll
        for (int off = 32; off > 0; off >>= 1) dot += __shfl_xor(dot, off);
        float sg = 1.0f / (1.0f + expf(-dot));
        float2 ov = *(float2*)(out + (size_t)node * DIM + lane * 2);
        ov.x += sg * hx; ov.y += sg * hy;
        *(float2*)(out + (size_t)node * DIM + lane * 2) = ov;
        float sn = src_norm[node];
        __half2 pw; pw.x = __float2half(sn * hx); pw.y = __float2half(sn * hy);
        *(__half2*)(pnext + (size_t)node * DIM + lane * 2) = pw;
    }
}

// final: out[n] = sum_k sg_k[n] * (p_k[n] * isrc[n])   (h_k = p_k / src_norm)
__global__ void final_combine(const __half* __restrict__ pbase, const float* __restrict__ sg,
                              const float* __restrict__ isrc, float* __restrict__ out, int n) {
    int lane = threadIdx.x & 63;
    int wave = (blockIdx.x * blockDim.x + threadIdx.x) >> 6;
    int nwaves = (gridDim.x * blockDim.x) >> 6;
    for (int node = wave; node < n; node += nwaves) {
        float iv = isrc[node];
        float ax = 0.0f, ay = 0.0f;
        #pragma unroll
        for (int k = 0; k <= KSTEPS; ++k) {
            float g = sg[(size_t)k * n + node] * iv;
            float2 fv = __half22float2(
                *(const __half2*)(pbase + ((size_t)k * n + node) * DIM + lane * 2));
            ax += g * fv.x; ay += g * fv.y;
        }
        *(float2*)(out + (size_t)node * DIM + lane * 2) = make_float2(ax, ay);
    }
}

extern "C" void kernel_launch(void* const* d_in, const int* in_sizes, int n_in,
                              void* d_out, int out_size, void* d_ws, size_t ws_size,
                              hipStream_t stream) {
    const float* feats = (const float*)d_in[0];
    const float* s     = (const float*)d_in[1];
    const int*   src   = (const int*)d_in[2];
    const int*   dst   = (const int*)d_in[3];
    float* out = (float*)d_out;
    const int E = in_sizes[2];

    // Workspace layout
    int*   outc     = (int*)d_ws;                         // N
    int*   cur      = outc + NODES;                       // N (in-degree after build)
    float* src_norm = (float*)(cur + NODES);              // N
    float* isrc     = src_norm + NODES;                   // N
    float* dst_norm = isrc + NODES;                       // N
    float* sg       = dst_norm + NODES;                   // 11*N
    int*   csr      = (int*)(sg + (size_t)(KSTEPS + 1) * NODES);   // N*CAP
    __half* pbase   = (__half*)(csr + (size_t)NODES * CAP);

    const size_t head_bytes = (size_t)(2 * NODES) * 4 + (size_t)(3 + KSTEPS + 1) * NODES * 4
                            + (size_t)NODES * CAP * 4;
    const size_t pbuf = (size_t)NODES * DIM * sizeof(__half);   // 25.6 MB each
    const bool main_path = ws_size >= head_bytes + (size_t)(KSTEPS + 1) * pbuf;

    // Bucket storage aliased over the first TWO p-slabs (p0/p1). In both paths
    // those slabs are first written by combine0_* / gather(k=1), which run
    // after degree_scatter completes (stream-ordered) -> aliasing is safe.
    // gdc/gsc: 2*64 u32; dpairs/spairs: NR*GBCAP u32 = 14.1 MB each (28.2 MB < 51.2 MB).
    unsigned* gdc    = (unsigned*)pbase;
    unsigned* gsc    = gdc + 64;
    unsigned* dpairs = gsc + 64;
    unsigned* spairs = dpairs + (size_t)NR * GBCAP;

    hipMemsetAsync(gdc, 0, 2 * 64 * sizeof(unsigned), stream);
    const int nbatch = (E + BT - 1) / BT;
    bucket_agg<<<nbatch, 256, 0, stream>>>(src, dst, gdc, gsc, dpairs, spairs, E);
    degree_scatter<<<2 * NR, 256, 0, stream>>>(gdc, gsc, dpairs, spairs, cur, outc, csr);
    norm_kernel<<<(NODES + 255) / 256, 256, 0, stream>>>(outc, cur, src_norm, isrc, dst_norm, NODES);

    const int ngrid = (NODES * 64 + 255) / 256;
    if (main_path) {
        // p_k stored contiguously: p_k = pbase + k*N*D
        combine0_main<<<ngrid, 256, 0, stream>>>(feats, s, src_norm, pbase, sg, NODES);
        for (int k = 1; k <= KSTEPS; ++k) {
            const __half* pprev = pbase + (size_t)(k - 1) * NODES * DIM;
            __half* pnext = pbase + (size_t)k * NODES * DIM;
            gather_main<<<ngrid, 256, 0, stream>>>(pprev, src_norm, dst_norm, cur, csr, s,
                                                   pnext, sg + (size_t)k * NODES, NODES);
        }
        final_combine<<<ngrid, 256, 0, stream>>>(pbase, sg, isrc, out, NODES);
    } else {
        __half* pA = pbase;
        __half* pB = pbase + (size_t)NODES * DIM;
        combine0_fb<<<ngrid, 256, 0, stream>>>(feats, s, src_norm, pA, out, NODES);
        const __half* pcur = pA;
        for (int k = 1; k <= KSTEPS; ++k) {
            __half* pnext = (k & 1) ? pB : pA;
            gather_fb<<<ngrid, 256, 0, stream>>>(pcur, src_norm, dst_norm, cur, csr, s,
                                                 pnext, out, NODES);
            pcur = pnext;
        }
    }
}